// Round 7
// baseline (90.548 us; speedup 1.0000x reference)
//
#include <hip/hip_runtime.h>
#include <cmath>

// BKT forward, B independent students, serial T-step fp32 recurrence.
//
// NUMERICS (R1-R3): harness validates vs fp32 numpy recompute; recurrence
// amplifies rounding ~2e5x over 512 steps -> must replicate np's fp32 op
// order exactly (no FMA contraction, separate rounded mul/add/div, fp64
// sigmoid rounded once). Passing absmax = 0.0039. DO NOT reassociate.
//
// PERF history:
//  R3: per-step scattered stores -> WRITE 1.05 GB (3.9x), 268 us
//  R4: reg-buffered stores, compiler sank them (VGPR=32) -> 437 MB, 153 us
//  R5: __launch_bounds__(256,1) freed regs -> 122 us
//  R6: LDS-transpose store phase, full 128B-line stores -> 90 us
//  R7 (this): STEPS 32->64. Each output row is one 2KB HBM page; per pass a
//      page received only 128B and was not revisited for ~5.6us -> one page
//      ACTIVATION per 128B written (activate-rate limited, ~50% BW). 256B
//      per visit halves activations on both write and y-read streams.
//      LDS = 256 rows x 64 floats = exactly 64KB, XOR-swizzled 16B slots
//      (write: lane=row, slot q -> phys q^(row&15); read: 4 rows x 16 slots
//      per instr) -> both sides perfectly bank-balanced (8cy min for b128).
//      VGPR ~290 is free: grid-limited 1 wave/SIMD, launch_bounds(256,1).

#define SWZS(row, s) ((((s) ^ ((row) & 15))) * 4)  // float offset of 16B slot s

__device__ __forceinline__ int comp4(const int4& v, int c) {
    return c == 0 ? v.x : c == 1 ? v.y : c == 2 ? v.z : v.w;
}

__global__ __launch_bounds__(256, 1) void bkt_fwd(
    const int* __restrict__ X,          // (B,4) int32 indices
    const int* __restrict__ Y,          // (B,T) int32 observations {0,1}
    const float* __restrict__ learn_w,  // (N,1)
    const float* __restrict__ guess_w,
    const float* __restrict__ slip_w,
    const float* __restrict__ prior_w,
    float* __restrict__ out,            // corrects (B,T) then latents (B,T)
    int B, int T)                       // requires B % 256 == 0, T % 64 == 0
{
#pragma clang fp contract(off)
    const int tid = threadIdx.x;
    const int b = blockIdx.x * 256 + tid;

    __shared__ float xp[256 * 64];      // 64 KB exactly; cr-pass then lt-pass

    const int4 xi = *reinterpret_cast<const int4*>(X + (size_t)b * 4);
    // correctly-rounded fp32 sigmoids via fp64
    const float l = (float)(1.0 / (1.0 + exp(-(double)learn_w[xi.x])));
    const float g = (float)(1.0 / (1.0 + exp(-(double)guess_w[xi.y])));
    const float s = (float)(1.0 / (1.0 + exp(-(double)slip_w[xi.z])));
    const float p = (float)(1.0 / (1.0 + exp(-(double)prior_w[xi.w])));

    const float oms = 1.0f - s;              // (1-s)
    const float omg = 1.0f - g;              // (1-g)
    const float lo  = 1e-6f;
    const float hi  = (float)(1.0 - 1e-6);   // fp32(1-EPS)
    float latent = p;

    const int4* __restrict__ yv = reinterpret_cast<const int4*>(Y + (size_t)b * T);

    // store-phase mapping: instr q covers 4 rows (wv*64 + q*4 + rsub),
    // 16 lanes per row covering the row's 256B chunk (slot = 16B).
    const int wv = tid >> 6, ln = tid & 63;
    const int rsub = ln >> 4;                // 0..3
    const int slot = ln & 15;                // 0..15
    float* __restrict__ lwr = xp + tid * 64; // this thread's LDS row (writes)
    float* __restrict__ gco = out + (size_t)(blockIdx.x * 256 + wv * 64 + rsub) * T + slot * 4;
    float* __restrict__ gla = gco + (size_t)B * T;

    constexpr int STEPS = 64, NQ = 16;
    const int nOuter = T / STEPS;            // 8

    // software pipeline: preload y chunk for o=0 (1 wave/SIMD -> no TLP)
    int4 yq[NQ], yqn[NQ];
    #pragma unroll
    for (int q = 0; q < NQ; ++q) yq[q] = yv[q];

    for (int o = 0; o < nOuter; ++o) {
        if (o + 1 < nOuter) {
            #pragma unroll
            for (int q = 0; q < NQ; ++q) yqn[q] = yv[(o + 1) * NQ + q];
        }

        float cr[STEPS], lt[STEPS];
        #pragma unroll
        for (int j = 0; j < STEPS; ++j) {    // fully unrolled: static indexing
            // every statement = one IEEE fp32 rounding, np's association order
            const float a       = latent * oms;       // latent*(1-s)
            const float omlat   = 1.0f - latent;      // (1-latent)
            const float t1      = omlat * g;          // (1-latent)*g
            const float correct = a + t1;
            const float n0      = latent * s;         // latent*s
            const float t2      = omlat * omg;        // (1-latent)*(1-g)
            const float d0      = n0 + t2;
            const bool hit = comp4(yq[j >> 2], j & 3) > 0;   // y_t > 0.5
            const float num = hit ? a : n0;
            const float den = hit ? correct : d0;
            const float k   = num / den;              // IEEE fp32 divide
            cr[j] = correct;
            lt[j] = latent;                           // recorded BEFORE update
            const float omk = 1.0f - k;
            const float t3  = omk * l;                // (1-k)*l
            const float nxt = k + t3;                 // k + (1-k)*l
            latent = fminf(fmaxf(nxt, lo), hi);       // clip
        }

        const int colo = o * STEPS;

        // ---- corrects: regs -> swizzled LDS -> 4-rows-x-256B dense stores ----
        #pragma unroll
        for (int q = 0; q < NQ; ++q)
            *reinterpret_cast<float4*>(lwr + SWZS(tid, q)) =
                make_float4(cr[4*q], cr[4*q+1], cr[4*q+2], cr[4*q+3]);
        __builtin_amdgcn_wave_barrier();   // order ds_write before ds_read
        #pragma unroll
        for (int q = 0; q < NQ; ++q) {
            const int rl = wv * 64 + q * 4 + rsub;
            const float4 v = *reinterpret_cast<const float4*>(xp + rl * 64 + SWZS(rl, slot));
            *reinterpret_cast<float4*>(gco + (size_t)(q * 4) * T + colo) = v;
        }
        __builtin_amdgcn_wave_barrier();   // order reads before lt-pass overwrite

        // ---- latents ----
        #pragma unroll
        for (int q = 0; q < NQ; ++q)
            *reinterpret_cast<float4*>(lwr + SWZS(tid, q)) =
                make_float4(lt[4*q], lt[4*q+1], lt[4*q+2], lt[4*q+3]);
        __builtin_amdgcn_wave_barrier();
        #pragma unroll
        for (int q = 0; q < NQ; ++q) {
            const int rl = wv * 64 + q * 4 + rsub;
            const float4 v = *reinterpret_cast<const float4*>(xp + rl * 64 + SWZS(rl, slot));
            *reinterpret_cast<float4*>(gla + (size_t)(q * 4) * T + colo) = v;
        }
        __builtin_amdgcn_wave_barrier();

        #pragma unroll
        for (int q = 0; q < NQ; ++q) yq[q] = yqn[q];
    }
}

extern "C" void kernel_launch(void* const* d_in, const int* in_sizes, int n_in,
                              void* d_out, int out_size, void* d_ws, size_t ws_size,
                              hipStream_t stream)
{
    const int*   X  = (const int*)d_in[0];
    const int*   Y  = (const int*)d_in[1];
    const float* lw = (const float*)d_in[2];
    const float* gw = (const float*)d_in[3];
    const float* sw = (const float*)d_in[4];
    const float* pw = (const float*)d_in[5];
    float* out = (float*)d_out;

    const int B = in_sizes[0] / 4;   // 65536
    const int T = in_sizes[1] / B;   // 512

    const int threads = 256;
    const int blocks = B / threads;  // B % 256 == 0
    bkt_fwd<<<blocks, threads, 0, stream>>>(X, Y, lw, gw, sw, pw, out, B, T);
}